// Round 9
// baseline (232.665 us; speedup 1.0000x reference)
//
#include <hip/hip_runtime.h>

#define TB 512
#define TF 1280
#define TH 2560
#define TK 8
#define TE 9
#define SLOT 8192

typedef unsigned short ushortT;
typedef unsigned long long u64;
typedef __attribute__((ext_vector_type(8))) short short8;
typedef __attribute__((ext_vector_type(4))) short short4v;
typedef __attribute__((ext_vector_type(4))) float floatx4;

__device__ __forceinline__ unsigned short f2bf(float f) {
  union { float f; unsigned u; } v; v.f = f;
  unsigned r = v.u + 0x7fffu + ((v.u >> 16) & 1u);   // RNE
  return (unsigned short)(r >> 16);
}

// pack two fp32 -> (bf16(a) low, bf16(b) high), RNE, via v_perm
__device__ __forceinline__ unsigned pk2(float a, float b) {
  union { float f; unsigned u; } ua, ub; ua.f = a; ub.f = b;
  unsigned ra = ua.u + 0x7fffu + ((ua.u >> 16) & 1u);
  unsigned rb = ub.u + 0x7fffu + ((ub.u >> 16) & 1u);
  return __builtin_amdgcn_perm(rb, ra, 0x07060302);  // {ra[31:16], rb[31:16]}
}

__device__ __forceinline__ void gl_lds16(const void* g, void* l) {
  __builtin_amdgcn_global_load_lds(
      (const __attribute__((address_space(1))) unsigned*)g,
      (__attribute__((address_space(3))) unsigned*)l, 16, 0, 0);
}

// st-swizzle for the 8KB slots (64B rows): involution, XORs row bits 1-3
// (o bits 7-9) into chunk bits 4-6. Frag ds_read_b128 2-way max (free).
__device__ __forceinline__ int swz(int o) { return o ^ (((o >> 7) & 7) << 4); }

// ---- small prep: W1 prepack ELIMINATED (fused into gemm1) ------------------
// blocks [0,320):    x  -> pre-swizzled 8KB slots [mt][kt32]
// blocks [320,1040): W2 -> bf16 transposed [e][n][h]
// blocks [1040,1076): zero the fp32 logits accumulator
__global__ __launch_bounds__(256) void prep_all(
    const float* __restrict__ x, const float* __restrict__ W2,
    char* __restrict__ Apk, ushortT* __restrict__ W2t,
    float* __restrict__ lacc) {
  const int b = blockIdx.x;
  const int t = threadIdx.x;
  if (b < 320) {
    const int i = b * 256 + t;              // [0, 81920) chunks of 16B
    const int cc = i & 511, slot = i >> 9;  // 160 slots of 512 chunks
    const int khalf = slot & 1;
    const int kt = (slot >> 1) % 20;
    const int mt = slot / 40;
    const int op = cc * 16;
    const int o = swz(op);
    const int r = o >> 6, k2 = (o & 63) >> 1;
    const float* src = x + (long)(mt * 128 + r) * TF + kt * 64 + khalf * 32 + k2;
    floatx4 v0 = *(const floatx4*)(src);
    floatx4 v1 = *(const floatx4*)(src + 4);
    u64 q0 = (u64)pk2(v0.x, v0.y) | ((u64)pk2(v0.z, v0.w) << 32);
    u64 q1 = (u64)pk2(v1.x, v1.y) | ((u64)pk2(v1.z, v1.w) << 32);
    *(ulonglong2*)(Apk + (long)i * 16) = make_ulonglong2(q0, q1);
  } else if (b < 1040) {
    const int o = (b - 320) * 256 + t;      // exactly TE*TK*TH
    const int hcol = o % TH;
    const int rest = o / TH;
    const int n = rest & 7;
    const int e = rest >> 3;
    W2t[(long)(e * TK + n) * TH + hcol] = f2bf(W2[((long)e * TH + hcol) * TK + n]);
  } else {
    const int i = ((b - 1040) * 256 + t) * 4;
    if (i < TE * TB * TK)
      *(floatx4*)(lacc + i) = (floatx4){0.f, 0.f, 0.f, 0.f};
  }
}

// ---- standalone prepass (fallback path only) -------------------------------
__global__ __launch_bounds__(256) void prepass(
    const float* __restrict__ x, const float* __restrict__ W2,
    u64* __restrict__ xq, ushortT* __restrict__ W2t) {
  const int i = blockIdx.x * 256 + threadIdx.x;
  if (i < 320 * 512) {
    const int kq = i >> 9, m = i & 511;
    floatx4 v = *(const floatx4*)(x + (long)m * TF + kq * 4);
    xq[i] = (u64)pk2(v.x, v.y) | ((u64)pk2(v.z, v.w) << 32);
  } else {
    const int o = i - 320 * 512;
    if (o < TE * TK * TH) {
      const int hcol = o % TH;
      const int rest = o / TH;
      const int n = rest & 7;
      const int e = rest >> 3;
      W2t[(long)(e * TK + n) * TH + hcol] = f2bf(W2[((long)e * TH + hcol) * TK + n]);
    }
  }
}

// ---- fused gemm1+gemm2, W1 read DIRECTLY (fp32) with in-loop convert -------
// A (x): gl_lds from pre-swizzled Apk slots (proven R8 path), double-buffered
// at lds[0..16K). B (W1): per tile, 16 coalesced scalar fp32 loads/thread
// issued EARLY; after MFMA + vmcnt(0), pk2-convert to k-quads and ds_write
// into lds[16K..32K) double buffer using the SAME swizzled 64B-row layout,
// so fragment reads (oA/oB + swz) are unchanged from R8. Removes the entire
// W1 prepack kernel (118 MB read + 59 MB write) and its 59 MB re-read.
__global__ __launch_bounds__(256, 4) void gemm1_fused(
    const char* __restrict__ Apk, const float* __restrict__ W1,
    const float* __restrict__ b1, const ushortT* __restrict__ W2t,
    float* __restrict__ lacc) {
  __shared__ __align__(16) char lds[32768];
  const int t = threadIdx.x;
  const int lane = t & 63, w = t >> 6;      // 4 waves
  const int wm = w >> 1, wn = w & 1;
  const int lm = lane & 15, lq = lane >> 4;
  const int bid0 = blockIdx.x;
  const int bs = (bid0 & 7) * 90 + (bid0 >> 3);   // bijective: 720 = 8*90
  const int mt = bs & 3;
  const int ct = bs >> 2;
  const int nt = ct % 20, e = ct / 20;

  const char* Ab = Apk + (long)mt * 40 * SLOT;
  const int nB = t & 127;                   // col within the 128-wide tile
  const int gB = t >> 7;                    // k-half (16 k each)
  const float* Wcol = W1 + (long)e * TF * TH + nt * 128 + nB;

  int oA[4], oB[4];
#pragma unroll
  for (int mi = 0; mi < 4; ++mi)
    oA[mi] = swz((wm * 64 + mi * 16 + lm) * 64 + lq * 16);
#pragma unroll
  for (int ni = 0; ni < 4; ++ni)
    oB[ni] = swz((wn * 64 + ni * 16 + lm) * 64 + lq * 16);

  auto STAGE_A = [&](int tile) {
    if (tile >= 40) return;
    char* dst = lds + (tile & 1) * 8192 + w * 1024;   // per-wave stripe
    const char* sa = Ab + (long)tile * SLOT;
    gl_lds16(sa + t * 16, dst);
    gl_lds16(sa + 4096 + t * 16, dst + 4096);
  };

  float bf32[16];
  auto BLOAD = [&](int tile) {              // 16 coalesced scalar loads
    if (tile >= 40) return;
    const float* p = Wcol + (long)(tile * 32 + gB * 16) * TH;
#pragma unroll
    for (int q = 0; q < 16; ++q) bf32[q] = p[(long)q * TH];
  };
  auto BSTORE = [&](int tile) {             // convert + 4 u64 swizzled writes
    if (tile >= 40) return;
    char* bb = lds + 16384 + (tile & 1) * 8192;
#pragma unroll
    for (int q = 0; q < 4; ++q) {
      const int k4 = gB * 16 + q * 4;
      u64 qw = (u64)pk2(bf32[q * 4 + 0], bf32[q * 4 + 1])
             | ((u64)pk2(bf32[q * 4 + 2], bf32[q * 4 + 3]) << 32);
      *(u64*)(bb + swz(nB * 64 + k4 * 2)) = qw;
    }
  };

  floatx4 acc[4][4];
#pragma unroll
  for (int i = 0; i < 4; ++i)
#pragma unroll
    for (int j = 0; j < 4; ++j) acc[i][j] = (floatx4){0.f, 0.f, 0.f, 0.f};

  STAGE_A(0);
  BLOAD(0);
  asm volatile("s_waitcnt vmcnt(0)" ::: "memory");
  BSTORE(0);
  asm volatile("s_waitcnt lgkmcnt(0)" ::: "memory");
  __builtin_amdgcn_s_barrier();

  for (int j = 0; j < 40; ++j) {
    const char* bufA = lds + (j & 1) * 8192;
    const char* bufB = lds + 16384 + (j & 1) * 8192;
    STAGE_A(j + 1);                         // gl_lds -> A[(j+1)&1]
    BLOAD(j + 1);                           // fp32 -> regs (in flight)
    short8 af[4], bfr[4];
#pragma unroll
    for (int mi = 0; mi < 4; ++mi)
      af[mi] = *(const short8*)(bufA + oA[mi]);
#pragma unroll
    for (int ni = 0; ni < 4; ++ni)
      bfr[ni] = *(const short8*)(bufB + oB[ni]);
    asm volatile("s_waitcnt lgkmcnt(0)" ::: "memory");
    __builtin_amdgcn_sched_barrier(0);
    __builtin_amdgcn_s_setprio(1);
#pragma unroll
    for (int mi = 0; mi < 4; ++mi)
#pragma unroll
      for (int ni = 0; ni < 4; ++ni)
        acc[mi][ni] = __builtin_amdgcn_mfma_f32_16x16x32_bf16(af[mi], bfr[ni], acc[mi][ni], 0, 0, 0);
    __builtin_amdgcn_s_setprio(0);
    asm volatile("s_waitcnt vmcnt(0)" ::: "memory");  // A in LDS, B in regs
    BSTORE(j + 1);                          // other B buffer; readers retired
    asm volatile("s_waitcnt lgkmcnt(0)" ::: "memory");
    __builtin_amdgcn_s_barrier();
  }
  // loop exits fully drained (tile-40 ops were no-ops) -> LDS reusable

  // ---- epilogue A: pre-issue W2t B-frags (global, L3-hot), K=128 slice -----
  short8 bq[4];
  {
    const ushortT* wp = W2t + ((long)(e * TK + (lm < 8 ? lm : 0))) * TH
                        + nt * 128 + lq * 8;
#pragma unroll
    for (int kk = 0; kk < 4; ++kk) bq[kk] = *(const short8*)(wp + kk * 32);
    if (lm >= 8) {
#pragma unroll
      for (int kk = 0; kk < 4; ++kk) bq[kk] = (short8)0;
    }
  }

  // ---- epilogue B: relu'd h tile (128x128) -> LDS bf16, XOR-swizzled rows --
  // element (lrow,lcol) at byte (lrow*256 + lcol*2) ^ ((lrow&7)<<4); 32KB fits
#pragma unroll
  for (int ni = 0; ni < 4; ++ni) {
    const int lcol = wn * 64 + ni * 16 + lm;
    const float bias = b1[e * TH + nt * 128 + lcol];
#pragma unroll
    for (int mi = 0; mi < 4; ++mi) {
      const int lr0 = wm * 64 + mi * 16 + lq * 4;
      floatx4 c = acc[mi][ni];
#pragma unroll
      for (int r = 0; r < 4; ++r) {
        float v = c[r] + bias;
        v = v > 0.f ? v : 0.f;
        const int lrow = lr0 + r;
        const int o = (lrow * 256 + lcol * 2) ^ ((lrow & 7) << 4);
        *(ushortT*)(lds + o) = f2bf(v);
      }
    }
  }
  __syncthreads();

  // ---- epilogue C: in-block gemm2, 2 row-tiles per wave, K=128 -------------
  // XOR applied AFTER adding the column offset (no carry).
  floatx4 acc2[2];
  acc2[0] = (floatx4){0.f, 0.f, 0.f, 0.f};
  acc2[1] = (floatx4){0.f, 0.f, 0.f, 0.f};
#pragma unroll
  for (int rt = 0; rt < 2; ++rt) {
    const int row = (w * 2 + rt) * 16 + lm;
    const int rowb = row * 256;
    const int sx = (row & 7) << 4;
#pragma unroll
    for (int kk = 0; kk < 4; ++kk) {
      short8 a = *(const short8*)(lds + ((rowb + kk * 64 + lq * 16) ^ sx));
      acc2[rt] = __builtin_amdgcn_mfma_f32_16x16x32_bf16(a, bq[kk], acc2[rt], 0, 0, 0);
    }
  }
  if (lm < 8) {
#pragma unroll
    for (int rt = 0; rt < 2; ++rt) {
      const int growb = mt * 128 + (w * 2 + rt) * 16 + lq * 4;
#pragma unroll
      for (int r = 0; r < 4; ++r)
        atomicAdd(&lacc[((long)e * TB + growb + r) * TK + lm], acc2[rt][r]);
    }
  }
}

// ---- finish: bias + logits out + softmax + leaf path products --------------
__global__ __launch_bounds__(256) void finish(
    const float* __restrict__ lacc, const float* __restrict__ b2,
    float* __restrict__ out, float* __restrict__ logits_out) {
  const int b = blockIdx.x * 256 + threadIdx.x;
  if (b >= TB) return;
  float pr[TE][TK];
#pragma unroll
  for (int e = 0; e < TE; ++e) {
    float lg[TK];
    float mx = -1e30f;
#pragma unroll
    for (int k = 0; k < TK; ++k) {
      lg[k] = lacc[((long)e * TB + b) * TK + k] + b2[e * TK + k];
      logits_out[((long)e * TB + b) * TK + k] = lg[k];
      mx = fmaxf(mx, lg[k]);
    }
    float sm = 0.f;
#pragma unroll
    for (int k = 0; k < TK; ++k) { pr[e][k] = __expf(lg[k] - mx); sm += pr[e][k]; }
    const float inv = 1.f / sm;
#pragma unroll
    for (int k = 0; k < TK; ++k) pr[e][k] *= inv;
  }
  float* op = out + (long)b * 73;
  op[0] = 1.0f;
#pragma unroll
  for (int i = 0; i < 8; ++i) op[1 + i] = pr[0][i];
#pragma unroll
  for (int i = 0; i < 8; ++i)
#pragma unroll
    for (int j = 0; j < 8; ++j) op[9 + i * 8 + j] = pr[0][i] * pr[1 + i][j];
}

// ---- fallback gemm1 (used only if ws too small) ----------------------------
__global__ __launch_bounds__(256) void gemm1_fb(
    const float* __restrict__ x, const float* __restrict__ W1,
    const float* __restrict__ b1, ushortT* __restrict__ h) {
  __shared__ __align__(16) ushortT As[128 * 40];
  __shared__ __align__(16) ushortT Bs[128 * 40];
  const int t = threadIdx.x;
  const int tileN = blockIdx.x;
  const int e = tileN / 20;
  const int hbase = (tileN % 20) * 128;
  const int m0 = blockIdx.y * 128;
  const int lane = t & 63, w = t >> 6;
  const int wm = w & 1, wn = w >> 1;
  const int lm = lane & 15, lq = lane >> 4;
  const int lk = lq * 8;
  floatx4 acc[4][4];
#pragma unroll
  for (int i = 0; i < 4; ++i)
#pragma unroll
    for (int j = 0; j < 4; ++j) acc[i][j] = (floatx4){0.f, 0.f, 0.f, 0.f};
  const float* wp = W1 + (long)e * TF * TH + hbase;
  const int cA = (t & 7) * 4;
  const int mA = t >> 3;
  const int nBf = t & 127;
  const int gBf = t >> 7;
  for (int kt = 0; kt < TF / 32; ++kt) {
    const int k0 = kt * 32;
    if (kt) __syncthreads();
#pragma unroll
    for (int i = 0; i < 4; ++i) {
      const int m = mA + 32 * i;
      floatx4 v = *(const floatx4*)(x + (long)(m0 + m) * TF + k0 + cA);
      short4v s; s.x = f2bf(v.x); s.y = f2bf(v.y); s.z = f2bf(v.z); s.w = f2bf(v.w);
      *(short4v*)&As[m * 40 + cA] = s;
    }
    {
      const float* bp = wp + (long)k0 * TH + nBf;
#pragma unroll
      for (int q = 0; q < 4; ++q) {
        const int k4 = gBf * 16 + q * 4;
        float f0 = bp[(long)(k4 + 0) * TH];
        float f1 = bp[(long)(k4 + 1) * TH];
        float f2 = bp[(long)(k4 + 2) * TH];
        float f3 = bp[(long)(k4 + 3) * TH];
        short4v s; s.x = f2bf(f0); s.y = f2bf(f1); s.z = f2bf(f2); s.w = f2bf(f3);
        *(short4v*)&Bs[nBf * 40 + k4] = s;
      }
    }
    __syncthreads();
    short8 af[4], bfr[4];
#pragma unroll
    for (int mg = 0; mg < 4; ++mg)
      af[mg] = *(const short8*)&As[(wm * 64 + mg * 16 + lm) * 40 + lk];
#pragma unroll
    for (int ng = 0; ng < 4; ++ng)
      bfr[ng] = *(const short8*)&Bs[(wn * 64 + ng * 16 + lm) * 40 + lk];
#pragma unroll
    for (int mg = 0; mg < 4; ++mg)
#pragma unroll
      for (int ng = 0; ng < 4; ++ng)
        acc[mg][ng] = __builtin_amdgcn_mfma_f32_16x16x32_bf16(af[mg], bfr[ng], acc[mg][ng], 0, 0, 0);
  }
#pragma unroll
  for (int mg = 0; mg < 4; ++mg) {
    const int row = m0 + wm * 64 + mg * 16 + lq * 4;
#pragma unroll
    for (int ng = 0; ng < 4; ++ng) {
      const int col = hbase + wn * 64 + ng * 16 + lm;
      const float bias = b1[e * TH + col];
      floatx4 c = acc[mg][ng];
#pragma unroll
      for (int r = 0; r < 4; ++r) {
        float v = c[r] + bias;
        v = v > 0.f ? v : 0.f;
        h[((long)e * TB + row + r) * TH + col] = f2bf(v);
      }
    }
  }
}

// ---- fallback gemm2 + softmax ----------------------------------------------
__global__ __launch_bounds__(512) void gemm2_softmax(
    const ushortT* __restrict__ h, const ushortT* __restrict__ W2t,
    const float* __restrict__ b2, float* __restrict__ logits_out,
    float* __restrict__ probs) {
  __shared__ float Ls[8][16][8];
  const int t = threadIdx.x;
  const int lane = t & 63, w = t >> 6;      // 8 waves
  const int e = blockIdx.x >> 5;
  const int r0 = (blockIdx.x & 31) * 16;
  const int lm = lane & 15, lq = lane >> 4;

  const ushortT* hp = h + ((long)(e * TB + r0 + lm)) * TH + w * 320 + lq * 8;
  const int bn = lm < 8 ? lm : 7;
  const ushortT* wp = W2t + ((long)(e * TK + bn)) * TH + w * 320 + lq * 8;

  floatx4 acc = (floatx4){0.f, 0.f, 0.f, 0.f};
#pragma unroll
  for (int kt = 0; kt < 10; ++kt) {
    short8 a = *(const short8*)(hp + kt * 32);
    short8 b = *(const short8*)(wp + kt * 32);
    acc = __builtin_amdgcn_mfma_f32_16x16x32_bf16(a, b, acc, 0, 0, 0);
  }
  if (lm < 8) {
#pragma unroll
    for (int r = 0; r < 4; ++r) Ls[w][lq * 4 + r][lm] = acc[r];
  }
  __syncthreads();
  if (w == 0 && lm < 8) {
    const float bias = b2[e * TK + lm];
#pragma unroll
    for (int r = 0; r < 4; ++r) {
      const int row = lq * 4 + r;
      float v = Ls[0][row][lm] + Ls[1][row][lm] + Ls[2][row][lm] + Ls[3][row][lm]
              + Ls[4][row][lm] + Ls[5][row][lm] + Ls[6][row][lm] + Ls[7][row][lm]
              + bias;
      float mx = v;
      mx = fmaxf(mx, __shfl_xor(mx, 1, 64));
      mx = fmaxf(mx, __shfl_xor(mx, 2, 64));
      mx = fmaxf(mx, __shfl_xor(mx, 4, 64));
      float ex = __expf(v - mx);
      float sm = ex;
      sm += __shfl_xor(sm, 1, 64);
      sm += __shfl_xor(sm, 2, 64);
      sm += __shfl_xor(sm, 4, 64);
      const long idx = ((long)e * TB + r0 + row) * TK + lm;
      logits_out[idx] = v;
      probs[idx] = ex / sm;
    }
  }
}

// ---- fallback leaf path products -------------------------------------------
__global__ __launch_bounds__(256) void leafk(const float* __restrict__ probs,
                                             float* __restrict__ out) {
  const int idx = blockIdx.x * 256 + threadIdx.x;
  if (idx >= TB * 73) return;
  const int b = idx / 73, c = idx % 73;
  float v;
  if (c == 0) {
    v = 1.0f;
  } else if (c < 9) {
    v = probs[(long)b * TK + (c - 1)];
  } else {
    const int i = (c - 9) >> 3, j = (c - 9) & 7;
    v = probs[(long)b * TK + i] * probs[((long)(1 + i) * TB + b) * TK + j];
  }
  out[idx] = v;
}

extern "C" void kernel_launch(void* const* d_in, const int* in_sizes, int n_in,
                              void* d_out, int out_size, void* d_ws, size_t ws_size,
                              hipStream_t stream) {
  const float* x  = (const float*)d_in[0];
  const float* W1 = (const float*)d_in[1];
  const float* b1 = (const float*)d_in[2];
  const float* W2 = (const float*)d_in[3];
  const float* b2 = (const float*)d_in[4];
  float* out = (float*)d_out;

  // ws layout (offsets unchanged; W1p region no longer used)
  ushortT* h     = (ushortT*)d_ws;                       // 23,592,960 B (fallback only)
  float*   lacc  = (float*)((char*)d_ws + 23592960);     //    147,456 B
  char*    Apk   = (char*)d_ws + 23740416;               //  1,310,720 B (160x8K)
  ushortT* W2t   = (ushortT*)((char*)d_ws + 25051136);   //    368,640 B
  const size_t NEED = 25419776;
  float* logits_out = out + TB * 73;

  if (ws_size >= NEED) {
    prep_all<<<1076, 256, 0, stream>>>(x, W2, Apk, W2t, lacc);
    gemm1_fused<<<720, 256, 0, stream>>>(Apk, W1, b1, W2t, lacc);
    finish<<<2, 256, 0, stream>>>(lacc, b2, out, logits_out);
  } else {
    prepass<<<1360, 256, 0, stream>>>(x, W2, (u64*)Apk, W2t);
    gemm1_fb<<<dim3(180, 4), 256, 0, stream>>>(x, W1, b1, h);
    gemm2_softmax<<<TE * 32, 512, 0, stream>>>(h, W2t, b2, logits_out, lacc);
    leafk<<<(TB * 73 + 255) / 256, 256, 0, stream>>>(lacc, out);
  }
}

// Round 10
// 225.414 us; speedup vs baseline: 1.0322x; 1.0322x over previous
//
#include <hip/hip_runtime.h>

#define TB 512
#define TF 1280
#define TH 2560
#define TK 8
#define TE 9
#define SLOT 8192
#define BUFSZ 16384

typedef unsigned short ushortT;
typedef unsigned long long u64;
typedef __attribute__((ext_vector_type(8))) short short8;
typedef __attribute__((ext_vector_type(4))) short short4v;
typedef __attribute__((ext_vector_type(4))) float floatx4;

__device__ __forceinline__ unsigned short f2bf(float f) {
  union { float f; unsigned u; } v; v.f = f;
  unsigned r = v.u + 0x7fffu + ((v.u >> 16) & 1u);   // RNE
  return (unsigned short)(r >> 16);
}

// pack two fp32 -> (bf16(a) low, bf16(b) high), RNE, via v_perm
__device__ __forceinline__ unsigned pk2(float a, float b) {
  union { float f; unsigned u; } ua, ub; ua.f = a; ub.f = b;
  unsigned ra = ua.u + 0x7fffu + ((ua.u >> 16) & 1u);
  unsigned rb = ub.u + 0x7fffu + ((ub.u >> 16) & 1u);
  return __builtin_amdgcn_perm(rb, ra, 0x07060302);  // {ra[31:16], rb[31:16]}
}

__device__ __forceinline__ void gl_lds16(const void* g, void* l) {
  __builtin_amdgcn_global_load_lds(
      (const __attribute__((address_space(1))) unsigned*)g,
      (__attribute__((address_space(3))) unsigned*)l, 16, 0, 0);
}

// st-swizzle for the 8KB slots (64B rows): involution, XORs row bits 1-3
// (o bits 7-9) into chunk bits 4-6. Frag ds_read_b128 2-way max (free).
__device__ __forceinline__ int swz(int o) { return o ^ (((o >> 7) & 7) << 4); }

// ---- merged prep (R6/R8 version: W1 prepack restored) ----------------------
// blocks [0,7200):     W1 -> pre-swizzled 8KB slots [e][nt][kt32]
// blocks [7200,7520):  x  -> same format [mt][kt32]
// blocks [7520,8240):  W2 -> bf16 transposed [e][n][h]
// blocks [8240,8276):  zero the fp32 logits accumulator
__global__ __launch_bounds__(256) void prep_all(
    const float* __restrict__ x, const float* __restrict__ W1,
    const float* __restrict__ W2,
    char* __restrict__ Apk, ushortT* __restrict__ W2t, char* __restrict__ W1p,
    float* __restrict__ lacc) {
  const int b = blockIdx.x;
  const int t = threadIdx.x;
  if (b < 7200) {
    __shared__ ushortT Ts[128 * 40];        // [n][k2], stride 40 shorts
    const int khalf = b & 1;
    const int kt = (b >> 1) % 20;
    const int nt = ((b >> 1) / 20) % 20;
    const int e = b / 800;
    const int kbase = kt * 64 + khalf * 32;
    const int nbase = nt * 128;
    const int kr = t >> 5, n4 = (t & 31) * 4;
#pragma unroll
    for (int kk = 0; kk < 4; ++kk) {
      const int k2 = kk * 8 + kr;
      floatx4 v = *(const floatx4*)(W1 + ((long)e * TF + kbase + k2) * TH + nbase + n4);
#pragma unroll
      for (int i = 0; i < 4; ++i) Ts[(n4 + i) * 40 + k2] = f2bf(v[i]);
    }
    __syncthreads();
    char* dstbase = W1p + (long)b * SLOT;   // slot index == b by construction
#pragma unroll
    for (int p = 0; p < 2; ++p) {
      const int op = (p * 256 + t) * 16;
      const int o = swz(op);
      const int r = o >> 6, k2c = (o & 63) >> 1;
      short8 v = *(const short8*)&Ts[r * 40 + k2c];
      *(short8*)(dstbase + op) = v;
    }
  } else if (b < 7520) {
    const int i = (b - 7200) * 256 + t;     // [0, 81920) chunks of 16B
    const int cc = i & 511, slot = i >> 9;  // 160 slots of 512 chunks
    const int khalf = slot & 1;
    const int kt = (slot >> 1) % 20;
    const int mt = slot / 40;
    const int op = cc * 16;
    const int o = swz(op);
    const int r = o >> 6, k2 = (o & 63) >> 1;
    const float* src = x + (long)(mt * 128 + r) * TF + kt * 64 + khalf * 32 + k2;
    floatx4 v0 = *(const floatx4*)(src);
    floatx4 v1 = *(const floatx4*)(src + 4);
    u64 q0 = (u64)pk2(v0.x, v0.y) | ((u64)pk2(v0.z, v0.w) << 32);
    u64 q1 = (u64)pk2(v1.x, v1.y) | ((u64)pk2(v1.z, v1.w) << 32);
    *(ulonglong2*)(Apk + (long)i * 16) = make_ulonglong2(q0, q1);
  } else if (b < 8240) {
    const int o = (b - 7520) * 256 + t;
    if (o < TE * TK * TH) {
      const int hcol = o % TH;
      const int rest = o / TH;
      const int n = rest & 7;
      const int e = rest >> 3;
      W2t[(long)(e * TK + n) * TH + hcol] = f2bf(W2[((long)e * TH + hcol) * TK + n]);
    }
  } else {
    const int i = ((b - 8240) * 256 + t) * 4;
    if (i < TE * TB * TK)
      *(floatx4*)(lacc + i) = (floatx4){0.f, 0.f, 0.f, 0.f};
  }
}

// ---- standalone prepass (fallback path only) -------------------------------
__global__ __launch_bounds__(256) void prepass(
    const float* __restrict__ x, const float* __restrict__ W2,
    u64* __restrict__ xq, ushortT* __restrict__ W2t) {
  const int i = blockIdx.x * 256 + threadIdx.x;
  if (i < 320 * 512) {
    const int kq = i >> 9, m = i & 511;
    floatx4 v = *(const floatx4*)(x + (long)m * TF + kq * 4);
    xq[i] = (u64)pk2(v.x, v.y) | ((u64)pk2(v.z, v.w) << 32);
  } else {
    const int o = i - 320 * 512;
    if (o < TE * TK * TH) {
      const int hcol = o % TH;
      const int rest = o / TH;
      const int n = rest & 7;
      const int e = rest >> 3;
      W2t[(long)(e * TK + n) * TH + hcol] = f2bf(W2[((long)e * TH + hcol) * TK + n]);
    }
  }
}

// ---- fused gemm1+gemm2: 128x128, 2-phase BK=32, 3-buffer COUNTED vmcnt -----
// R9 post-mortem: W1-direct regressed (1.9M bank conflicts, serial converts)
// -> reverted to prepacked W1. This round applies T4 to R8's 2-phase loop:
// 3 LDS buffers (48KB, 3 blocks/CU, 720 all co-resident) and vmcnt(4) in
// steady state — tile j+2's 4 loads stay IN FLIGHT across the barrier, giving
// a full tile of latency slack (was: drain to 0 every tile = m233's 72% stall).
// Buffer (j+2)%3 == (j-1)%3: its ds_reads retired before end-of-(j-1) barrier.
// Tail j>=38: stage stream ends -> drain with vmcnt(0) (also guards epilogue).
__global__ __launch_bounds__(256, 3) void gemm1_fused(
    const char* __restrict__ Apk, const char* __restrict__ Bpk,
    const float* __restrict__ b1, const ushortT* __restrict__ W2t,
    float* __restrict__ lacc) {
  __shared__ __align__(16) char lds[49152];
  const int t = threadIdx.x;
  const int lane = t & 63, w = t >> 6;      // 4 waves
  const int wm = w >> 1, wn = w & 1;
  const int lm = lane & 15, lq = lane >> 4;
  const int bid0 = blockIdx.x;
  const int bs = (bid0 & 7) * 90 + (bid0 >> 3);   // bijective: 720 = 8*90
  const int mt = bs & 3;
  const int ct = bs >> 2;
  const int nt = ct % 20, e = ct / 20;

  const char* Ab = Apk + (long)mt * 40 * SLOT;
  const char* Bb = Bpk + (long)((e * 20 + nt) * 40) * SLOT;

  int oA[4], oB[4];
#pragma unroll
  for (int mi = 0; mi < 4; ++mi)
    oA[mi] = swz((wm * 64 + mi * 16 + lm) * 64 + lq * 16);
#pragma unroll
  for (int ni = 0; ni < 4; ++ni)
    oB[ni] = swz((wn * 64 + ni * 16 + lm) * 64 + lq * 16);

  auto STAGE = [&](int tile, int buf3) {   // one BK=32 tile: A slot + B slot
    if (tile >= 40) return;
    char* dst = lds + buf3 * BUFSZ + w * 1024;      // per-wave stripe!
    const char* sa = Ab + (long)tile * SLOT;
    const char* sb = Bb + (long)tile * SLOT;
    gl_lds16(sa + t * 16, dst);
    gl_lds16(sa + 4096 + t * 16, dst + 4096);
    gl_lds16(sb + t * 16, dst + 8192);
    gl_lds16(sb + 4096 + t * 16, dst + 12288);
  };

  floatx4 acc[4][4];
#pragma unroll
  for (int i = 0; i < 4; ++i)
#pragma unroll
    for (int j = 0; j < 4; ++j) acc[i][j] = (floatx4){0.f, 0.f, 0.f, 0.f};

  // prologue: tiles 0,1 in flight; wait tile 0 only (4 of 8 outstanding)
  STAGE(0, 0);
  STAGE(1, 1);
  asm volatile("s_waitcnt vmcnt(4)" ::: "memory");
  __builtin_amdgcn_s_barrier();

  int cur = 0, nxt2 = 2;                   // j%3 and (j+2)%3 rotating indices
  for (int j = 0; j < 40; ++j) {
    const char* buf = lds + cur * BUFSZ;
    STAGE(j + 2, nxt2);                    // buf (j+2)%3 == (j-1)%3: free
    short8 af[4], bfr[4];
#pragma unroll
    for (int mi = 0; mi < 4; ++mi)
      af[mi] = *(const short8*)(buf + oA[mi]);
#pragma unroll
    for (int ni = 0; ni < 4; ++ni)
      bfr[ni] = *(const short8*)(buf + 8192 + oB[ni]);
    asm volatile("s_waitcnt lgkmcnt(0)" ::: "memory");
    __builtin_amdgcn_sched_barrier(0);
    __builtin_amdgcn_s_setprio(1);
#pragma unroll
    for (int mi = 0; mi < 4; ++mi)
#pragma unroll
      for (int ni = 0; ni < 4; ++ni)
        acc[mi][ni] = __builtin_amdgcn_mfma_f32_16x16x32_bf16(af[mi], bfr[ni], acc[mi][ni], 0, 0, 0);
    __builtin_amdgcn_s_setprio(0);
    if (j >= 38) {                         // stage stream ended: must drain
      asm volatile("s_waitcnt vmcnt(0)" ::: "memory");
    } else {                               // counted: tile j+1 landed,
      asm volatile("s_waitcnt vmcnt(4)" ::: "memory");  // j+2 stays in flight
    }
    __builtin_amdgcn_s_barrier();
    cur = cur == 2 ? 0 : cur + 1;
    nxt2 = nxt2 == 2 ? 0 : nxt2 + 1;
  }
  // loop exits fully drained -> LDS reusable

  // ---- epilogue A: pre-issue W2t B-frags (global, L3-hot), K=128 slice -----
  short8 bq[4];
  {
    const ushortT* wp = W2t + ((long)(e * TK + (lm < 8 ? lm : 0))) * TH
                        + nt * 128 + lq * 8;
#pragma unroll
    for (int kk = 0; kk < 4; ++kk) bq[kk] = *(const short8*)(wp + kk * 32);
    if (lm >= 8) {
#pragma unroll
      for (int kk = 0; kk < 4; ++kk) bq[kk] = (short8)0;
    }
  }

  // ---- epilogue B: relu'd h tile (128x128) -> LDS bf16, XOR-swizzled rows --
  // element (lrow,lcol) at byte (lrow*256 + lcol*2) ^ ((lrow&7)<<4); 32KB fits
#pragma unroll
  for (int ni = 0; ni < 4; ++ni) {
    const int lcol = wn * 64 + ni * 16 + lm;
    const float bias = b1[e * TH + nt * 128 + lcol];
#pragma unroll
    for (int mi = 0; mi < 4; ++mi) {
      const int lr0 = wm * 64 + mi * 16 + lq * 4;
      floatx4 c = acc[mi][ni];
#pragma unroll
      for (int r = 0; r < 4; ++r) {
        float v = c[r] + bias;
        v = v > 0.f ? v : 0.f;
        const int lrow = lr0 + r;
        const int o = (lrow * 256 + lcol * 2) ^ ((lrow & 7) << 4);
        *(ushortT*)(lds + o) = f2bf(v);
      }
    }
  }
  __syncthreads();

  // ---- epilogue C: in-block gemm2, 2 row-tiles per wave, K=128 -------------
  // XOR applied AFTER adding the column offset (no carry).
  floatx4 acc2[2];
  acc2[0] = (floatx4){0.f, 0.f, 0.f, 0.f};
  acc2[1] = (floatx4){0.f, 0.f, 0.f, 0.f};
#pragma unroll
  for (int rt = 0; rt < 2; ++rt) {
    const int row = (w * 2 + rt) * 16 + lm;
    const int rowb = row * 256;
    const int sx = (row & 7) << 4;
#pragma unroll
    for (int kk = 0; kk < 4; ++kk) {
      short8 a = *(const short8*)(lds + ((rowb + kk * 64 + lq * 16) ^ sx));
      acc2[rt] = __builtin_amdgcn_mfma_f32_16x16x32_bf16(a, bq[kk], acc2[rt], 0, 0, 0);
    }
  }
  if (lm < 8) {
#pragma unroll
    for (int rt = 0; rt < 2; ++rt) {
      const int growb = mt * 128 + (w * 2 + rt) * 16 + lq * 4;
#pragma unroll
      for (int r = 0; r < 4; ++r)
        atomicAdd(&lacc[((long)e * TB + growb + r) * TK + lm], acc2[rt][r]);
    }
  }
}

// ---- finish: bias + logits out + softmax + leaf path products --------------
__global__ __launch_bounds__(256) void finish(
    const float* __restrict__ lacc, const float* __restrict__ b2,
    float* __restrict__ out, float* __restrict__ logits_out) {
  const int b = blockIdx.x * 256 + threadIdx.x;
  if (b >= TB) return;
  float pr[TE][TK];
#pragma unroll
  for (int e = 0; e < TE; ++e) {
    float lg[TK];
    float mx = -1e30f;
#pragma unroll
    for (int k = 0; k < TK; ++k) {
      lg[k] = lacc[((long)e * TB + b) * TK + k] + b2[e * TK + k];
      logits_out[((long)e * TB + b) * TK + k] = lg[k];
      mx = fmaxf(mx, lg[k]);
    }
    float sm = 0.f;
#pragma unroll
    for (int k = 0; k < TK; ++k) { pr[e][k] = __expf(lg[k] - mx); sm += pr[e][k]; }
    const float inv = 1.f / sm;
#pragma unroll
    for (int k = 0; k < TK; ++k) pr[e][k] *= inv;
  }
  float* op = out + (long)b * 73;
  op[0] = 1.0f;
#pragma unroll
  for (int i = 0; i < 8; ++i) op[1 + i] = pr[0][i];
#pragma unroll
  for (int i = 0; i < 8; ++i)
#pragma unroll
    for (int j = 0; j < 8; ++j) op[9 + i * 8 + j] = pr[0][i] * pr[1 + i][j];
}

// ---- fallback gemm1 (used only if ws too small) ----------------------------
__global__ __launch_bounds__(256) void gemm1_fb(
    const float* __restrict__ x, const float* __restrict__ W1,
    const float* __restrict__ b1, ushortT* __restrict__ h) {
  __shared__ __align__(16) ushortT As[128 * 40];
  __shared__ __align__(16) ushortT Bs[128 * 40];
  const int t = threadIdx.x;
  const int tileN = blockIdx.x;
  const int e = tileN / 20;
  const int hbase = (tileN % 20) * 128;
  const int m0 = blockIdx.y * 128;
  const int lane = t & 63, w = t >> 6;
  const int wm = w & 1, wn = w >> 1;
  const int lm = lane & 15, lq = lane >> 4;
  const int lk = lq * 8;
  floatx4 acc[4][4];
#pragma unroll
  for (int i = 0; i < 4; ++i)
#pragma unroll
    for (int j = 0; j < 4; ++j) acc[i][j] = (floatx4){0.f, 0.f, 0.f, 0.f};
  const float* wp = W1 + (long)e * TF * TH + hbase;
  const int cA = (t & 7) * 4;
  const int mA = t >> 3;
  const int nBf = t & 127;
  const int gBf = t >> 7;
  for (int kt = 0; kt < TF / 32; ++kt) {
    const int k0 = kt * 32;
    if (kt) __syncthreads();
#pragma unroll
    for (int i = 0; i < 4; ++i) {
      const int m = mA + 32 * i;
      floatx4 v = *(const floatx4*)(x + (long)(m0 + m) * TF + k0 + cA);
      short4v s; s.x = f2bf(v.x); s.y = f2bf(v.y); s.z = f2bf(v.z); s.w = f2bf(v.w);
      *(short4v*)&As[m * 40 + cA] = s;
    }
    {
      const float* bp = wp + (long)k0 * TH + nBf;
#pragma unroll
      for (int q = 0; q < 4; ++q) {
        const int k4 = gBf * 16 + q * 4;
        float f0 = bp[(long)(k4 + 0) * TH];
        float f1 = bp[(long)(k4 + 1) * TH];
        float f2 = bp[(long)(k4 + 2) * TH];
        float f3 = bp[(long)(k4 + 3) * TH];
        short4v s; s.x = f2bf(f0); s.y = f2bf(f1); s.z = f2bf(f2); s.w = f2bf(f3);
        *(short4v*)&Bs[nBf * 40 + k4] = s;
      }
    }
    __syncthreads();
    short8 af[4], bfr[4];
#pragma unroll
    for (int mg = 0; mg < 4; ++mg)
      af[mg] = *(const short8*)&As[(wm * 64 + mg * 16 + lm) * 40 + lk];
#pragma unroll
    for (int ng = 0; ng < 4; ++ng)
      bfr[ng] = *(const short8*)&Bs[(wn * 64 + ng * 16 + lm) * 40 + lk];
#pragma unroll
    for (int mg = 0; mg < 4; ++mg)
#pragma unroll
      for (int ng = 0; ng < 4; ++ng)
        acc[mg][ng] = __builtin_amdgcn_mfma_f32_16x16x32_bf16(af[mg], bfr[ng], acc[mg][ng], 0, 0, 0);
  }
#pragma unroll
  for (int mg = 0; mg < 4; ++mg) {
    const int row = m0 + wm * 64 + mg * 16 + lq * 4;
#pragma unroll
    for (int ng = 0; ng < 4; ++ng) {
      const int col = hbase + wn * 64 + ng * 16 + lm;
      const float bias = b1[e * TH + col];
      floatx4 c = acc[mg][ng];
#pragma unroll
      for (int r = 0; r < 4; ++r) {
        float v = c[r] + bias;
        v = v > 0.f ? v : 0.f;
        h[((long)e * TB + row + r) * TH + col] = f2bf(v);
      }
    }
  }
}

// ---- fallback gemm2 + softmax ----------------------------------------------
__global__ __launch_bounds__(512) void gemm2_softmax(
    const ushortT* __restrict__ h, const ushortT* __restrict__ W2t,
    const float* __restrict__ b2, float* __restrict__ logits_out,
    float* __restrict__ probs) {
  __shared__ float Ls[8][16][8];
  const int t = threadIdx.x;
  const int lane = t & 63, w = t >> 6;      // 8 waves
  const int e = blockIdx.x >> 5;
  const int r0 = (blockIdx.x & 31) * 16;
  const int lm = lane & 15, lq = lane >> 4;

  const ushortT* hp = h + ((long)(e * TB + r0 + lm)) * TH + w * 320 + lq * 8;
  const int bn = lm < 8 ? lm : 7;
  const ushortT* wp = W2t + ((long)(e * TK + bn)) * TH + w * 320 + lq * 8;

  floatx4 acc = (floatx4){0.f, 0.f, 0.f, 0.f};
#pragma unroll
  for (int kt = 0; kt < 10; ++kt) {
    short8 a = *(const short8*)(hp + kt * 32);
    short8 b = *(const short8*)(wp + kt * 32);
    acc = __builtin_amdgcn_mfma_f32_16x16x32_bf16(a, b, acc, 0, 0, 0);
  }
  if (lm < 8) {
#pragma unroll
    for (int r = 0; r < 4; ++r) Ls[w][lq * 4 + r][lm] = acc[r];
  }
  __syncthreads();
  if (w == 0 && lm < 8) {
    const float bias = b2[e * TK + lm];
#pragma unroll
    for (int r = 0; r < 4; ++r) {
      const int row = lq * 4 + r;
      float v = Ls[0][row][lm] + Ls[1][row][lm] + Ls[2][row][lm] + Ls[3][row][lm]
              + Ls[4][row][lm] + Ls[5][row][lm] + Ls[6][row][lm] + Ls[7][row][lm]
              + bias;
      float mx = v;
      mx = fmaxf(mx, __shfl_xor(mx, 1, 64));
      mx = fmaxf(mx, __shfl_xor(mx, 2, 64));
      mx = fmaxf(mx, __shfl_xor(mx, 4, 64));
      float ex = __expf(v - mx);
      float sm = ex;
      sm += __shfl_xor(sm, 1, 64);
      sm += __shfl_xor(sm, 2, 64);
      sm += __shfl_xor(sm, 4, 64);
      const long idx = ((long)e * TB + r0 + row) * TK + lm;
      logits_out[idx] = v;
      probs[idx] = ex / sm;
    }
  }
}

// ---- fallback leaf path products -------------------------------------------
__global__ __launch_bounds__(256) void leafk(const float* __restrict__ probs,
                                             float* __restrict__ out) {
  const int idx = blockIdx.x * 256 + threadIdx.x;
  if (idx >= TB * 73) return;
  const int b = idx / 73, c = idx % 73;
  float v;
  if (c == 0) {
    v = 1.0f;
  } else if (c < 9) {
    v = probs[(long)b * TK + (c - 1)];
  } else {
    const int i = (c - 9) >> 3, j = (c - 9) & 7;
    v = probs[(long)b * TK + i] * probs[((long)(1 + i) * TB + b) * TK + j];
  }
  out[idx] = v;
}

extern "C" void kernel_launch(void* const* d_in, const int* in_sizes, int n_in,
                              void* d_out, int out_size, void* d_ws, size_t ws_size,
                              hipStream_t stream) {
  const float* x  = (const float*)d_in[0];
  const float* W1 = (const float*)d_in[1];
  const float* b1 = (const float*)d_in[2];
  const float* W2 = (const float*)d_in[3];
  const float* b2 = (const float*)d_in[4];
  float* out = (float*)d_out;

  // ws layout (offsets unchanged)
  ushortT* h     = (ushortT*)d_ws;                       // 23,592,960 B (fallback only)
  float*   lacc  = (float*)((char*)d_ws + 23592960);     //    147,456 B
  char*    Apk   = (char*)d_ws + 23740416;               //  1,310,720 B (160x8K)
  ushortT* W2t   = (ushortT*)((char*)d_ws + 25051136);   //    368,640 B
  char*    W1p   = (char*)d_ws + 25419776;               // 58,982,400 B (7200x8K)
  const size_t NEED = 25419776 + 58982400;               // 84,402,176 B
  float* logits_out = out + TB * 73;

  if (ws_size >= NEED) {
    prep_all<<<8276, 256, 0, stream>>>(x, W1, W2, Apk, W2t, W1p, lacc);
    gemm1_fused<<<720, 256, 0, stream>>>(Apk, W1p, b1, W2t, lacc);
    finish<<<2, 256, 0, stream>>>(lacc, b2, out, logits_out);
  } else {
    prepass<<<1360, 256, 0, stream>>>(x, W2, (u64*)Apk, W2t);
    gemm1_fb<<<dim3(180, 4), 256, 0, stream>>>(x, W1, b1, h);
    gemm2_softmax<<<TE * 32, 512, 0, stream>>>(h, W2t, b2, logits_out, lacc);
    leafk<<<(TB * 73 + 255) / 256, 256, 0, stream>>>(lacc, out);
  }
}